// Round 11
// baseline (676.745 us; speedup 1.0000x reference)
//
#include <hip/hip_runtime.h>
#include <hip/hip_bf16.h>
#include <stdint.h>

typedef __bf16 bf16x8 __attribute__((ext_vector_type(8)));
typedef float f32x4 __attribute__((ext_vector_type(4)));
typedef float fvec4 __attribute__((ext_vector_type(4)));
typedef unsigned short usvec4 __attribute__((ext_vector_type(4)));
typedef unsigned int ui32x4 __attribute__((ext_vector_type(4)));

#define AS3 __attribute__((address_space(3)))
#define AS1 __attribute__((address_space(1)))

static __device__ __forceinline__ unsigned short f2bf(float f) {
  unsigned int u = __float_as_uint(f);
  u += 0x7FFF + ((u >> 16) & 1);   // round-to-nearest-even
  return (unsigned short)(u >> 16);
}

// ---------------- fp32 -> bf16 conversion kernels ----------------

extern "C" __global__ void cvt_bf16_kernel(const float* __restrict__ src,
                                           unsigned short* __restrict__ dst,
                                           long n4) {
  long i = (long)blockIdx.x * blockDim.x + threadIdx.x;
  const long stride = (long)gridDim.x * blockDim.x;
  for (; i < n4; i += stride) {
    const fvec4 v = __builtin_nontemporal_load(&((const fvec4*)src)[i]);
    usvec4 o;
    o.x = f2bf(v.x); o.y = f2bf(v.y); o.z = f2bf(v.z); o.w = f2bf(v.w);
    ((usvec4*)dst)[i] = o;
  }
}

extern "C" __global__ void cvt_pad_kernel(const float* __restrict__ src,
                                          unsigned short* __restrict__ dst,
                                          long nsrc4, long ntot4) {
  long i = (long)blockIdx.x * blockDim.x + threadIdx.x;
  const long stride = (long)gridDim.x * blockDim.x;
  for (; i < ntot4; i += stride) {
    usvec4 o = {0, 0, 0, 0};
    if (i < nsrc4) {
      const fvec4 v = __builtin_nontemporal_load(&((const fvec4*)src)[i]);
      o.x = f2bf(v.x); o.y = f2bf(v.y); o.z = f2bf(v.z); o.w = f2bf(v.w);
    }
    ((usvec4*)dst)[i] = o;
  }
}

#define VMW(N) asm volatile("s_waitcnt vmcnt(" #N ")" ::: "memory")
#define BAR() do { __builtin_amdgcn_s_barrier(); \
                   __builtin_amdgcn_sched_barrier(0); } while (0)
#define LGKM0() do { asm volatile("s_waitcnt lgkmcnt(0)" ::: "memory"); \
                     __builtin_amdgcn_sched_barrier(0); } while (0)

// ============ launch1 kernel: 256x256, BK=64, round-8 structure ============
// (unchanged from round 10)

template <int MODE>
__global__ __launch_bounds__(512, 2)
void mla_gemm(const __hip_bfloat16* __restrict__ A0p,
              const __hip_bfloat16* __restrict__ B0p, int K0,
              unsigned short* __restrict__ qlora,
              const float* __restrict__ cosp,
              const float* __restrict__ sinp,
              float* __restrict__ out) {
  extern __shared__ __align__(128) char lds[];
  const int tid = threadIdx.x;
  const int lane = tid & 63;
  const int w = tid >> 6;
  const int wm = w >> 2, wn = w & 3;
  const int l15 = lane & 15, lhi = lane >> 4;
  const int srow8 = lane >> 3;
  const int swzc = ((lane & 7) ^ srow8) * 8;

  const int bm = (int)blockIdx.x >> 3;     // bn-major: XCD id == bn
  const int bn = (int)blockIdx.x & 7;
  const __hip_bfloat16* Aptr = A0p;
  const __hip_bfloat16* Bptr = B0p;
  const int K = K0;
  const long brow = (long)bm * 256;
  const int bcol = bn * 256;

  const __hip_bfloat16* aSt = Aptr + (brow + w * 16 + srow8) * (long)K + swzc;
  const __hip_bfloat16* bSt = Bptr + ((long)bcol + srow8) * (long)K + swzc;
  const int wj0 = w * 16, wj1 = w * 16 + 8;
  const int cb_j0 = (2 * (wj0 >> 5)) * 32 + (wj0 & 31);
  const int cb_j1 = (2 * (wj1 >> 5)) * 32 + (wj1 & 31);
  const int ldsWj = w * 2048;

  const int aRdRow = (wm * 64 + l15) * 128;
  const int bRdRow = (wn * 32 + l15) * 128;
  const int ck0 = (lhi ^ (l15 & 7)) * 16;

  f32x4 acc[8][4] = {};
  bf16x8 aF[4][2];
  bf16x8 bF[2][2][2];

  const int T = K >> 6;

  auto stage = [&](int u, int kt) {
    const int b = kt & 1;
    if (u < 2) {
      const int off = b * 32768 + u * 16384 + ldsWj;
      __builtin_amdgcn_global_load_lds((AS1 void*)(aSt + (long)(u * 128) * K + kt * 64),
                                       (AS3 void*)(lds + off), 16, 0, 0);
      __builtin_amdgcn_global_load_lds((AS1 void*)(aSt + (long)(u * 128 + 8) * K + kt * 64),
                                       (AS3 void*)(lds + off + 1024), 16, 0, 0);
    } else {
      const int h = u - 2;
      const int off = 65536 + b * 32768 + h * 16384 + ldsWj;
      __builtin_amdgcn_global_load_lds((AS1 void*)(bSt + (long)(cb_j0 + h * 32) * K + kt * 64),
                                       (AS3 void*)(lds + off), 16, 0, 0);
      __builtin_amdgcn_global_load_lds((AS1 void*)(bSt + (long)(cb_j1 + h * 32) * K + kt * 64),
                                       (AS3 void*)(lds + off + 1024), 16, 0, 0);
    }
  };
  auto readA = [&](int qh, int b) {
    const int base = b * 32768 + qh * 16384 + aRdRow;
    #pragma unroll
    for (int fr = 0; fr < 4; ++fr) {
      aF[fr][0] = *(const bf16x8*)(lds + base + fr * 2048 + ck0);
      aF[fr][1] = *(const bf16x8*)(lds + base + fr * 2048 + (ck0 ^ 64));
    }
  };
  auto readB = [&](int c, int b) {
    const int base = 65536 + b * 32768 + c * 16384 + bRdRow;
    #pragma unroll
    for (int fq = 0; fq < 2; ++fq) {
      bF[c][fq][0] = *(const bf16x8*)(lds + base + fq * 2048 + ck0);
      bF[c][fq][1] = *(const bf16x8*)(lds + base + fq * 2048 + (ck0 ^ 64));
    }
  };
  auto mmac = [&](int qh, int c) {
    __builtin_amdgcn_s_setprio(1);
    #pragma unroll
    for (int fr = 0; fr < 4; ++fr)
      #pragma unroll
      for (int fq = 0; fq < 2; ++fq) {
        acc[qh * 4 + fr][c * 2 + fq] = __builtin_amdgcn_mfma_f32_16x16x32_bf16(
            aF[fr][0], bF[c][fq][0], acc[qh * 4 + fr][c * 2 + fq], 0, 0, 0);
        acc[qh * 4 + fr][c * 2 + fq] = __builtin_amdgcn_mfma_f32_16x16x32_bf16(
            aF[fr][1], bF[c][fq][1], acc[qh * 4 + fr][c * 2 + fq], 0, 0, 0);
      }
    __builtin_amdgcn_s_setprio(0);
  };

  stage(0, 0); stage(2, 0); stage(3, 0); stage(1, 0);
  stage(0, 1); stage(2, 1); stage(3, 1); stage(1, 1);
  VMW(12);
  BAR();

  for (int t = 0; t < T - 2; ++t) {
    const int b = t & 1;
    readA(0, b); readB(0, b); if (t) stage(1, t + 1);
    VMW(10); BAR(); LGKM0(); mmac(0, 0);
    readB(1, b);
    VMW(8); BAR(); LGKM0(); mmac(0, 1);
    readA(1, b); stage(0, t + 2); stage(2, t + 2);
    BAR(); LGKM0(); mmac(1, 1);
    stage(3, t + 2);
    VMW(10); BAR(); mmac(1, 0);
  }
  {
    const int b = (T - 2) & 1;
    readA(0, b); readB(0, b); stage(1, T - 1);
    VMW(10); BAR(); LGKM0(); mmac(0, 0);
    readB(1, b);
    VMW(8); BAR(); LGKM0(); mmac(0, 1);
    readA(1, b);
    BAR(); LGKM0(); mmac(1, 1);
    VMW(4); BAR(); mmac(1, 0);
  }
  {
    const int b = (T - 1) & 1;
    readA(0, b); readB(0, b);
    VMW(2); BAR(); LGKM0(); mmac(0, 0);
    readB(1, b);
    VMW(0); BAR(); LGKM0(); mmac(0, 1);
    readA(1, b);
    BAR(); LGKM0(); mmac(1, 1);
    BAR(); mmac(1, 0);
  }

  const int wcol = bcol + wn * 64;
  const long rbase = brow + wm * 64;
  char* eplds = lds + w * 4096;

  auto storeTileF32 = [&](int i8, float* dst) {
    #pragma unroll
    for (int j = 0; j < 4; ++j)
      #pragma unroll
      for (int r = 0; r < 4; ++r)
        *(float*)(eplds + (lhi * 4 + r) * 256 + ((j >> 1) * 32 + (j & 1) * 16 + l15) * 4) =
            acc[i8][j][r];
    asm volatile("s_waitcnt lgkmcnt(0)" ::: "memory");
    #pragma unroll
    for (int t = 0; t < 4; ++t) {
      const int r16 = t * 4 + (lane >> 4);
      const f32x4 v = *(const f32x4*)(eplds + r16 * 256 + (lane & 15) * 16);
      const long row = rbase + (i8 >> 2) * 128 + (i8 & 3) * 16 + r16;
      __builtin_nontemporal_store(v, (f32x4*)(dst + row * 6720 + (lane & 15) * 4));
    }
  };
  auto storeTileBf16 = [&](int i8) {
    #pragma unroll
    for (int j = 0; j < 4; ++j)
      #pragma unroll
      for (int r = 0; r < 4; ++r)
        *(unsigned short*)(eplds + (lhi * 4 + r) * 128 +
                           ((j >> 1) * 32 + (j & 1) * 16 + l15) * 2) = f2bf(acc[i8][j][r]);
    asm volatile("s_waitcnt lgkmcnt(0)" ::: "memory");
    #pragma unroll
    for (int t = 0; t < 2; ++t) {
      const int r16 = t * 8 + (lane >> 3);
      const ui32x4 v = *(const ui32x4*)(eplds + r16 * 128 + (lane & 7) * 16);
      const long row = rbase + (i8 >> 2) * 128 + (i8 & 3) * 16 + r16;
      *(ui32x4*)((char*)qlora + (row * 1536 + wcol) * 2 + (lane & 7) * 16) = v;
    }
  };

  if (wcol < 1536) {
    #pragma unroll
    for (int i8 = 0; i8 < 8; ++i8) storeTileBf16(i8);
  } else {
    #pragma unroll
    for (int i8 = 0; i8 < 8; ++i8) storeTileF32(i8, out + wcol + 4672);
  }
}

// ============ launch2 kernel: 256x128, BK=32, 2 blocks/CU ============
// Round-11 change: B operand DIRECT global->register (skips LDS entirely;
// B panel is L2-resident via bn-major XCD swizzle). Double-buffered B regs
// (bFa/bFb, static names), one-phase prefetch. A stays 3-buf gload-LDS.
// LDS traffic per tile: was A16K+B8K writes + 64KB reads -> now A16K writes
// + 32KB reads. FIFO waits: steady VMW(6) = drain{B(t),A(t+1)}, leave
// {B(t+1),A(t+2)}; peel VMW(4) at T-2, VMW(0) at T-1. T always even (48/128).

__global__ __launch_bounds__(512, 4)
void mla_gemm2(const __hip_bfloat16* __restrict__ Aq,
               const __hip_bfloat16* __restrict__ Bq,
               const __hip_bfloat16* __restrict__ Ak,
               const __hip_bfloat16* __restrict__ Bk,
               const float* __restrict__ cosp,
               const float* __restrict__ sinp,
               float* __restrict__ out) {
  extern __shared__ __align__(128) char lds[];
  const int tid = threadIdx.x;
  const int lane = tid & 63;
  const int w = tid >> 6;
  const int wm = w >> 1, wn = w & 1;        // 4M x 2N
  const int l15 = lane & 15, lhi = lane >> 4;
  const int srow = lane >> 2;                       // staging row-in-16
  const int sslot = (lane & 3) ^ ((lane >> 3) & 3); // pre-swizzled src chunk

  const __hip_bfloat16* Ap;
  const __hip_bfloat16* Bp;
  int K, bm, bn;
  bool kpe;
  const int bid = (int)blockIdx.x;
  if (bid < 32) {
    kpe = true; bm = bid; bn = 0; Ap = Ak; Bp = Bk; K = 4096;
  } else {
    kpe = false;
    const int b2 = bid - 32;
    const int x = b2 & 7;          // XCD id
    const int i = b2 >> 3;
    const int r6 = i % 6;
    bm = i / 6;
    bn = x * 6 + r6;               // XCD x owns B col-panels {6x..6x+5}
    Ap = Aq; Bp = Bq; K = 1536;
  }
  const long brow = (long)bm * 256;
  const int bcol = bn * 128;

  // A staging: 256x32 (16KB) = 2 gloads/tile
  const __hip_bfloat16* aSt = Ap + (brow + w * 16 + srow) * (long)K + sslot * 8;
  // B direct-to-reg: lane reads B[(bcol + wn*64 + fc*16 + l15)][kt*32 + lhi*8]
  const __hip_bfloat16* bGl = Bp + ((long)bcol + wn * 64 + l15) * K + lhi * 8;

  const int kslot = (lhi ^ ((l15 >> 1) & 3)) * 16;
  const int aRd = (wm * 64 + l15) * 64 + kslot;           // + fr*1024 + bufOff

  f32x4 acc[4][4] = {};
  bf16x8 aF[4];
  bf16x8 bFa[4], bFb[4];
  const int T = K >> 5;
  const long fK16 = 16L * K;      // fragment col stride

  auto stageA = [&](int kt, int buf) {
    const int bo = buf * 16384;
    __builtin_amdgcn_global_load_lds((AS1 void*)(aSt + (long)kt * 32),
                                     (AS3 void*)(lds + bo + w * 1024), 16, 0, 0);
    __builtin_amdgcn_global_load_lds((AS1 void*)(aSt + 128L * K + (long)kt * 32),
                                     (AS3 void*)(lds + bo + 8192 + w * 1024), 16, 0, 0);
  };
  auto loadB = [&](int kt, bf16x8* dst) {
    const __hip_bfloat16* p = bGl + (long)kt * 32;
    #pragma unroll
    for (int fc = 0; fc < 4; ++fc)
      dst[fc] = *(const bf16x8*)(p + fc * fK16);
  };
  auto readA = [&](int buf) {
    const int bo = buf * 16384;
    #pragma unroll
    for (int f = 0; f < 4; ++f)
      aF[f] = *(const bf16x8*)(lds + bo + aRd + f * 1024);
  };
  auto mmac = [&](const bf16x8* bf) {
    __builtin_amdgcn_s_setprio(1);
    #pragma unroll
    for (int fr = 0; fr < 4; ++fr)
      #pragma unroll
      for (int fc = 0; fc < 4; ++fc)
        acc[fr][fc] = __builtin_amdgcn_mfma_f32_16x16x32_bf16(
            aF[fr], bf[fc], acc[fr][fc], 0, 0, 0);
    __builtin_amdgcn_s_setprio(0);
  };

  // prologue: FIFO = A(0):2, A(1):2, B(0):4 -> VMW(6) retires A(0)
  stageA(0, 0); stageA(1, 1);
  loadB(0, bFa);
  VMW(6);
  BAR();

  int cur = 0;
  // main: phases 0..T-3 steady (VMW(6)); T always even
  for (int t = 0; t < T - 2; t += 2) {
    // even phase: consume bFa, prefetch bFb
    readA(cur);
    loadB(t + 1, bFb);
    { int nx = cur + 2; if (nx >= 3) nx -= 3; stageA(t + 2, nx); }
    VMW(6); BAR(); LGKM0();
    mmac(bFa);
    cur = cur + 1; if (cur == 3) cur = 0;
    // odd phase: consume bFb, prefetch bFa
    readA(cur);
    loadB(t + 2, bFa);
    if (t + 3 < T) { int nx = cur + 2; if (nx >= 3) nx -= 3; stageA(t + 3, nx); }
    VMW(6); BAR(); LGKM0();
    mmac(bFb);
    cur = cur + 1; if (cur == 3) cur = 0;
  }
  // phase T-2 (even, uses bFa; prefetch B(T-1); no A stage)
  readA(cur);
  loadB(T - 1, bFb);
  VMW(4); BAR(); LGKM0();
  mmac(bFa);
  cur = cur + 1; if (cur == 3) cur = 0;
  // phase T-1 (odd, uses bFb; nothing outstanding after)
  readA(cur);
  VMW(0); LGKM0();
  mmac(bFb);

  // ---- epilogue: LDS-transposed full-line stores (wave-local 4KB) ----
  // acc[fr][fc][r]: row = brow + wm*64 + fr*16 + lhi*4 + r,
  //                 col = bcol + wn*64 + fc*16 + l15.
  BAR();   // all waves past K-loop before reusing LDS
  const int wcol = bcol + wn * 64;
  const long rbase = brow + wm * 64;
  char* eplds = lds + w * 4096;

  auto storeT = [&](int fr, int colBase, bool rope) {
    #pragma unroll
    for (int fc = 0; fc < 4; ++fc)
      #pragma unroll
      for (int r = 0; r < 4; ++r) {
        float v = acc[fr][fc][r];
        if (rope) {
          const long row = rbase + fr * 16 + lhi * 4 + r;
          const int d = fc * 16 + l15;
          const float rot = (fc < 2) ? -acc[fr][fc + 2][r] : acc[fr][fc - 2][r];
          v = v * cosp[row * 64 + d] + rot * sinp[row * 64 + d];
        }
        *(float*)(eplds + (lhi * 4 + r) * 256 + (fc * 16 + l15) * 4) = v;
      }
    asm volatile("s_waitcnt lgkmcnt(0)" ::: "memory");
    #pragma unroll
    for (int tt = 0; tt < 4; ++tt) {
      const int r16 = tt * 4 + (lane >> 4);
      const f32x4 vv = *(const f32x4*)(eplds + r16 * 256 + (lane & 15) * 16);
      const long row = rbase + fr * 16 + r16;
      __builtin_nontemporal_store(vv,
          (f32x4*)(out + row * 6720 + colBase + (lane & 15) * 4));
    }
  };

  if (kpe) {
    if (wn == 0) {   // cols 2048..2111 -> k_pe RoPE -> out 6144..6207
      #pragma unroll
      for (int fr = 0; fr < 4; ++fr) storeT(fr, 6144, true);
    }                // wn==1: pad cols, dropped
  } else if ((wcol % 192) == 128) {   // q_pe 64-block + RoPE
    #pragma unroll
    for (int fr = 0; fr < 4; ++fr) storeT(fr, wcol, true);
  } else {                            // q_nope copy
    #pragma unroll
    for (int fr = 0; fr < 4; ++fr) storeT(fr, wcol, false);
  }
}

// ---------------- launch ----------------

extern "C" void kernel_launch(void* const* d_in, const int* in_sizes, int n_in,
                              void* d_out, int out_size, void* d_ws, size_t ws_size,
                              hipStream_t stream) {
  const float* x    = (const float*)d_in[0];
  const float* cosp = (const float*)d_in[1];
  const float* sinp = (const float*)d_in[2];
  const float* Wqa  = (const float*)d_in[3];
  const float* Wqb  = (const float*)d_in[4];
  const float* Wkva = (const float*)d_in[5];
  float* out = (float*)d_out;

  char* ws = (char*)d_ws;
  __hip_bfloat16* xb  = (__hip_bfloat16*)ws;
  __hip_bfloat16* w1  = (__hip_bfloat16*)(ws + 67108864L);
  __hip_bfloat16* wqb = (__hip_bfloat16*)(ws + 67108864L + 17825792L);
  unsigned short* ql  = (unsigned short*)(ws + 67108864L + 17825792L + 18874368L);

  cvt_bf16_kernel<<<2048, 256, 0, stream>>>(x,   (unsigned short*)xb,  8192L * 4096 / 4);
  cvt_bf16_kernel<<<1024, 256, 0, stream>>>(Wqa, (unsigned short*)w1,  1536L * 4096 / 4);
  cvt_pad_kernel<<<640, 256, 0, stream>>>(Wkva, (unsigned short*)(w1 + 1536L * 4096),
                                          576L * 4096 / 4, 640L * 4096 / 4);
  cvt_bf16_kernel<<<1024, 256, 0, stream>>>(Wqb, (unsigned short*)wqb, 6144L * 1536 / 4);

  (void)hipFuncSetAttribute((const void*)&mla_gemm<0>,
                            hipFuncAttributeMaxDynamicSharedMemorySize, 131072);
  (void)hipFuncSetAttribute((const void*)&mla_gemm2,
                            hipFuncAttributeMaxDynamicSharedMemorySize, 49152);

  // launch1: x @ w1[0:2048] -> q_lora + compressed_kv. 256 blocks (1 round).
  mla_gemm<0><<<dim3(256), 512, 131072, stream>>>(xb, w1, 4096, ql, cosp, sinp, out);
  // launch2: 32 k_pe blocks (K=4096, LPT-first) + 1536 q blocks (K=1536),
  // 256x128 tiles, A 3-buf LDS (48KB) + B direct-to-reg, 2 blocks/CU.
  mla_gemm2<<<dim3(1568), 512, 49152, stream>>>((const __hip_bfloat16*)ql, wqb,
                                                xb, w1 + 2048L * 4096,
                                                cosp, sinp, out);
}

// Round 12
// 348.578 us; speedup vs baseline: 1.9414x; 1.9414x over previous
//
#include <hip/hip_runtime.h>
#include <hip/hip_bf16.h>
#include <stdint.h>

typedef __bf16 bf16x8 __attribute__((ext_vector_type(8)));
typedef float f32x4 __attribute__((ext_vector_type(4)));
typedef float fvec4 __attribute__((ext_vector_type(4)));
typedef unsigned short usvec4 __attribute__((ext_vector_type(4)));
typedef unsigned int ui32x4 __attribute__((ext_vector_type(4)));

#define AS3 __attribute__((address_space(3)))
#define AS1 __attribute__((address_space(1)))

static __device__ __forceinline__ unsigned short f2bf(float f) {
  unsigned int u = __float_as_uint(f);
  u += 0x7FFF + ((u >> 16) & 1);   // round-to-nearest-even
  return (unsigned short)(u >> 16);
}

// ---------------- fp32 -> bf16 conversion kernels ----------------

extern "C" __global__ void cvt_bf16_kernel(const float* __restrict__ src,
                                           unsigned short* __restrict__ dst,
                                           long n4) {
  long i = (long)blockIdx.x * blockDim.x + threadIdx.x;
  const long stride = (long)gridDim.x * blockDim.x;
  for (; i < n4; i += stride) {
    const fvec4 v = __builtin_nontemporal_load(&((const fvec4*)src)[i]);
    usvec4 o;
    o.x = f2bf(v.x); o.y = f2bf(v.y); o.z = f2bf(v.z); o.w = f2bf(v.w);
    ((usvec4*)dst)[i] = o;
  }
}

extern "C" __global__ void cvt_pad_kernel(const float* __restrict__ src,
                                          unsigned short* __restrict__ dst,
                                          long nsrc4, long ntot4) {
  long i = (long)blockIdx.x * blockDim.x + threadIdx.x;
  const long stride = (long)gridDim.x * blockDim.x;
  for (; i < ntot4; i += stride) {
    usvec4 o = {0, 0, 0, 0};
    if (i < nsrc4) {
      const fvec4 v = __builtin_nontemporal_load(&((const fvec4*)src)[i]);
      o.x = f2bf(v.x); o.y = f2bf(v.y); o.z = f2bf(v.z); o.w = f2bf(v.w);
    }
    ((usvec4*)dst)[i] = o;
  }
}

#define VMW(N) asm volatile("s_waitcnt vmcnt(" #N ")" ::: "memory")
#define BAR() do { __builtin_amdgcn_s_barrier(); \
                   __builtin_amdgcn_sched_barrier(0); } while (0)
#define LGKM0() do { asm volatile("s_waitcnt lgkmcnt(0)" ::: "memory"); \
                     __builtin_amdgcn_sched_barrier(0); } while (0)

// ============ 256x256 bf16 NT GEMM, BK=64 — EXACT round-8 source ============
// (restored verbatim, incl. both MODE branches; mla_gemm<1> is instantiated
// but not launched — reproduces round-8's compile/regalloc context, rule #19)

template <int MODE>
__global__ __launch_bounds__(512, 2)
void mla_gemm(const __hip_bfloat16* __restrict__ A0p,
              const __hip_bfloat16* __restrict__ B0p, int K0,
              const __hip_bfloat16* __restrict__ A1p,
              const __hip_bfloat16* __restrict__ B1p,
              unsigned short* __restrict__ qlora,
              const float* __restrict__ cosp,
              const float* __restrict__ sinp,
              float* __restrict__ out) {
  extern __shared__ __align__(128) char lds[];
  const int tid = threadIdx.x;
  const int lane = tid & 63;
  const int w = tid >> 6;
  const int wm = w >> 2, wn = w & 3;
  const int l15 = lane & 15, lhi = lane >> 4;
  const int srow8 = lane >> 3;
  const int swzc = ((lane & 7) ^ srow8) * 8;

  const __hip_bfloat16* Aptr;
  const __hip_bfloat16* Bptr;
  int K, bm, bn;
  bool isA2 = false;
  if constexpr (MODE == 0) {
    const int swz = ((int)blockIdx.x & 7) * 32 + ((int)blockIdx.x >> 3);
    bm = swz >> 3; bn = swz & 7;
    Aptr = A0p; Bptr = B0p; K = K0;
  } else {
    const int bid = (int)blockIdx.x;
    if (bid < 32) {
      isA2 = true; bm = bid; bn = 8; Aptr = A1p; Bptr = B1p; K = 4096;
    } else {
      const int b2 = bid - 32;
      const int swz = (b2 & 7) * 96 + (b2 >> 3);
      bm = swz / 24; bn = swz - bm * 24;
      Aptr = A0p; Bptr = B0p; K = K0;
    }
  }
  const long brow = (long)bm * 256;
  const int bcol = bn * 256;

  const __hip_bfloat16* aSt = Aptr + (brow + w * 16 + srow8) * (long)K + swzc;
  const __hip_bfloat16* bSt = Bptr + ((long)bcol + srow8) * (long)K + swzc;
  const int wj0 = w * 16, wj1 = w * 16 + 8;
  const int cb_j0 = (2 * (wj0 >> 5)) * 32 + (wj0 & 31);
  const int cb_j1 = (2 * (wj1 >> 5)) * 32 + (wj1 & 31);
  const int ldsWj = w * 2048;

  const int aRdRow = (wm * 64 + l15) * 128;
  const int bRdRow = (wn * 32 + l15) * 128;
  const int ck0 = (lhi ^ (l15 & 7)) * 16;

  f32x4 acc[8][4] = {};
  bf16x8 aF[4][2];
  bf16x8 bF[2][2][2];

  const int T = K >> 6;

  auto stage = [&](int u, int kt) {
    const int b = kt & 1;
    if (u < 2) {
      const int off = b * 32768 + u * 16384 + ldsWj;
      __builtin_amdgcn_global_load_lds((AS1 void*)(aSt + (long)(u * 128) * K + kt * 64),
                                       (AS3 void*)(lds + off), 16, 0, 0);
      __builtin_amdgcn_global_load_lds((AS1 void*)(aSt + (long)(u * 128 + 8) * K + kt * 64),
                                       (AS3 void*)(lds + off + 1024), 16, 0, 0);
    } else {
      const int h = u - 2;
      const int off = 65536 + b * 32768 + h * 16384 + ldsWj;
      __builtin_amdgcn_global_load_lds((AS1 void*)(bSt + (long)(cb_j0 + h * 32) * K + kt * 64),
                                       (AS3 void*)(lds + off), 16, 0, 0);
      __builtin_amdgcn_global_load_lds((AS1 void*)(bSt + (long)(cb_j1 + h * 32) * K + kt * 64),
                                       (AS3 void*)(lds + off + 1024), 16, 0, 0);
    }
  };
  auto readA = [&](int qh, int b) {
    const int base = b * 32768 + qh * 16384 + aRdRow;
    #pragma unroll
    for (int fr = 0; fr < 4; ++fr) {
      aF[fr][0] = *(const bf16x8*)(lds + base + fr * 2048 + ck0);
      aF[fr][1] = *(const bf16x8*)(lds + base + fr * 2048 + (ck0 ^ 64));
    }
  };
  auto readB = [&](int c, int b) {
    const int base = 65536 + b * 32768 + c * 16384 + bRdRow;
    #pragma unroll
    for (int fq = 0; fq < 2; ++fq) {
      bF[c][fq][0] = *(const bf16x8*)(lds + base + fq * 2048 + ck0);
      bF[c][fq][1] = *(const bf16x8*)(lds + base + fq * 2048 + (ck0 ^ 64));
    }
  };
  auto mmac = [&](int qh, int c) {
    __builtin_amdgcn_s_setprio(1);
    #pragma unroll
    for (int fr = 0; fr < 4; ++fr)
      #pragma unroll
      for (int fq = 0; fq < 2; ++fq) {
        acc[qh * 4 + fr][c * 2 + fq] = __builtin_amdgcn_mfma_f32_16x16x32_bf16(
            aF[fr][0], bF[c][fq][0], acc[qh * 4 + fr][c * 2 + fq], 0, 0, 0);
        acc[qh * 4 + fr][c * 2 + fq] = __builtin_amdgcn_mfma_f32_16x16x32_bf16(
            aF[fr][1], bF[c][fq][1], acc[qh * 4 + fr][c * 2 + fq], 0, 0, 0);
      }
    __builtin_amdgcn_s_setprio(0);
  };

  stage(0, 0); stage(2, 0); stage(3, 0); stage(1, 0);
  stage(0, 1); stage(2, 1); stage(3, 1); stage(1, 1);
  VMW(12);
  BAR();

  for (int t = 0; t < T - 2; ++t) {
    const int b = t & 1;
    readA(0, b); readB(0, b); if (t) stage(1, t + 1);
    VMW(10); BAR(); LGKM0(); mmac(0, 0);
    readB(1, b);
    VMW(8); BAR(); LGKM0(); mmac(0, 1);
    readA(1, b); stage(0, t + 2); stage(2, t + 2);
    BAR(); LGKM0(); mmac(1, 1);
    stage(3, t + 2);
    VMW(10); BAR(); mmac(1, 0);
  }
  {
    const int b = (T - 2) & 1;
    readA(0, b); readB(0, b); stage(1, T - 1);
    VMW(10); BAR(); LGKM0(); mmac(0, 0);
    readB(1, b);
    VMW(8); BAR(); LGKM0(); mmac(0, 1);
    readA(1, b);
    BAR(); LGKM0(); mmac(1, 1);
    VMW(4); BAR(); mmac(1, 0);
  }
  {
    const int b = (T - 1) & 1;
    readA(0, b); readB(0, b);
    VMW(2); BAR(); LGKM0(); mmac(0, 0);
    readB(1, b);
    VMW(0); BAR(); LGKM0(); mmac(0, 1);
    readA(1, b);
    BAR(); LGKM0(); mmac(1, 1);
    BAR(); mmac(1, 0);
  }

  const int wcol = bcol + wn * 64;
  const long rbase = brow + wm * 64;
  char* eplds = lds + w * 4096;

  auto storeTileF32 = [&](int i8, float* dst, bool rope) {
    #pragma unroll
    for (int j = 0; j < 4; ++j)
      #pragma unroll
      for (int r = 0; r < 4; ++r) {
        float v = acc[i8][j][r];
        if (rope) {
          const long row = rbase + (i8 >> 2) * 128 + (i8 & 3) * 16 + lhi * 4 + r;
          const int d = (j >> 1) * 32 + (j & 1) * 16 + l15;
          const float rot = (j < 2) ? -acc[i8][j + 2][r] : acc[i8][j - 2][r];
          v = v * cosp[row * 64 + d] + rot * sinp[row * 64 + d];
        }
        *(float*)(eplds + (lhi * 4 + r) * 256 + ((j >> 1) * 32 + (j & 1) * 16 + l15) * 4) = v;
      }
    asm volatile("s_waitcnt lgkmcnt(0)" ::: "memory");
    #pragma unroll
    for (int t = 0; t < 4; ++t) {
      const int r16 = t * 4 + (lane >> 4);
      const f32x4 v = *(const f32x4*)(eplds + r16 * 256 + (lane & 15) * 16);
      const long row = rbase + (i8 >> 2) * 128 + (i8 & 3) * 16 + r16;
      __builtin_nontemporal_store(v, (f32x4*)(dst + row * 6720 + (lane & 15) * 4));
    }
  };
  auto storeTileBf16 = [&](int i8) {
    #pragma unroll
    for (int j = 0; j < 4; ++j)
      #pragma unroll
      for (int r = 0; r < 4; ++r)
        *(unsigned short*)(eplds + (lhi * 4 + r) * 128 +
                           ((j >> 1) * 32 + (j & 1) * 16 + l15) * 2) = f2bf(acc[i8][j][r]);
    asm volatile("s_waitcnt lgkmcnt(0)" ::: "memory");
    #pragma unroll
    for (int t = 0; t < 2; ++t) {
      const int r16 = t * 8 + (lane >> 3);
      const ui32x4 v = *(const ui32x4*)(eplds + r16 * 128 + (lane & 7) * 16);
      const long row = rbase + (i8 >> 2) * 128 + (i8 & 3) * 16 + r16;
      *(ui32x4*)((char*)qlora + (row * 1536 + wcol) * 2 + (lane & 7) * 16) = v;
    }
  };

  if constexpr (MODE == 0) {
    if (wcol < 1536) {
      #pragma unroll
      for (int i8 = 0; i8 < 8; ++i8) storeTileBf16(i8);
    } else {
      #pragma unroll
      for (int i8 = 0; i8 < 8; ++i8) storeTileF32(i8, out + wcol + 4672, false);
    }
  } else {
    if (isA2) {
      if (wn == 0) {
        #pragma unroll
        for (int i8 = 0; i8 < 8; ++i8) storeTileF32(i8, out + 6144, true);
      }
    } else if ((wcol % 192) != 128) {
      #pragma unroll
      for (int i8 = 0; i8 < 8; ++i8) storeTileF32(i8, out + wcol, false);
    } else {
      #pragma unroll
      for (int i8 = 0; i8 < 8; ++i8) storeTileF32(i8, out + wcol, true);
    }
  }
}

// ============ launch2 kernel: 256x128, BK=32, 3-buf, 2 blocks/CU ============
// EXACT round-10 version (193 µs proven): B via LDS, bn-major XCD mapping.

__global__ __launch_bounds__(512, 4)
void mla_gemm2(const __hip_bfloat16* __restrict__ Aq,
               const __hip_bfloat16* __restrict__ Bq,
               const __hip_bfloat16* __restrict__ Ak,
               const __hip_bfloat16* __restrict__ Bk,
               const float* __restrict__ cosp,
               const float* __restrict__ sinp,
               float* __restrict__ out) {
  extern __shared__ __align__(128) char lds[];
  const int tid = threadIdx.x;
  const int lane = tid & 63;
  const int w = tid >> 6;
  const int wm = w >> 1, wn = w & 1;        // 4M x 2N
  const int l15 = lane & 15, lhi = lane >> 4;
  const int srow = lane >> 2;                       // staging row-in-16
  const int sslot = (lane & 3) ^ ((lane >> 3) & 3); // pre-swizzled src chunk

  const __hip_bfloat16* Ap;
  const __hip_bfloat16* Bp;
  int K, bm, bn;
  bool kpe;
  const int bid = (int)blockIdx.x;
  if (bid < 32) {
    kpe = true; bm = bid; bn = 0; Ap = Ak; Bp = Bk; K = 4096;
  } else {
    kpe = false;
    const int b2 = bid - 32;
    const int x = b2 & 7;          // XCD id
    const int i = b2 >> 3;
    const int r6 = i % 6;
    bm = i / 6;
    bn = x * 6 + r6;               // XCD x owns B col-panels {6x..6x+5}
    Ap = Aq; Bp = Bq; K = 1536;
  }
  const long brow = (long)bm * 256;
  const int bcol = bn * 128;

  const __hip_bfloat16* aSt = Ap + (brow + w * 16 + srow) * (long)K + sslot * 8;
  const __hip_bfloat16* bSt = Bp + ((long)bcol + w * 16 + srow) * (long)K + sslot * 8;

  const int kslot = (lhi ^ ((l15 >> 1) & 3)) * 16;
  const int aRd = (wm * 64 + l15) * 64 + kslot;           // + fr*1024 + bufOff
  const int bRd = 16384 + (wn * 64 + l15) * 64 + kslot;   // + fc*1024 + bufOff

  f32x4 acc[4][4] = {};
  const int T = K >> 5;

  auto stage = [&](int kt, int buf) {
    const int bo = buf * 24576;
    __builtin_amdgcn_global_load_lds((AS1 void*)(aSt + (long)kt * 32),
                                     (AS3 void*)(lds + bo + w * 1024), 16, 0, 0);
    __builtin_amdgcn_global_load_lds((AS1 void*)(aSt + 128L * K + (long)kt * 32),
                                     (AS3 void*)(lds + bo + 8192 + w * 1024), 16, 0, 0);
    __builtin_amdgcn_global_load_lds((AS1 void*)(bSt + (long)kt * 32),
                                     (AS3 void*)(lds + bo + 16384 + w * 1024), 16, 0, 0);
  };

  stage(0, 0); stage(1, 1);
  VMW(3);
  BAR();

  int cur = 0;
  for (int t = 0; t < T; ++t) {
    const int bo = cur * 24576;
    bf16x8 aF[4], bF[4];
    #pragma unroll
    for (int f = 0; f < 4; ++f)
      aF[f] = *(const bf16x8*)(lds + bo + aRd + f * 1024);
    #pragma unroll
    for (int f = 0; f < 4; ++f)
      bF[f] = *(const bf16x8*)(lds + bo + bRd + f * 1024);
    if (t + 2 < T) {
      int nx = cur + 2; if (nx >= 3) nx -= 3;
      stage(t + 2, nx);
      VMW(3);
    } else if (t + 2 == T) {
      VMW(0);
    }
    LGKM0();
    if (t < T - 1) BAR();
    __builtin_amdgcn_s_setprio(1);
    #pragma unroll
    for (int fr = 0; fr < 4; ++fr)
      #pragma unroll
      for (int fc = 0; fc < 4; ++fc)
        acc[fr][fc] = __builtin_amdgcn_mfma_f32_16x16x32_bf16(
            aF[fr], bF[fc], acc[fr][fc], 0, 0, 0);
    __builtin_amdgcn_s_setprio(0);
    cur = cur + 1; if (cur == 3) cur = 0;
  }

  const int wcol = bcol + wn * 64;
  const long rbase = brow + wm * 64;
  char* eplds = lds + w * 4096;

  auto storeT = [&](int fr, int colBase, bool rope) {
    #pragma unroll
    for (int fc = 0; fc < 4; ++fc)
      #pragma unroll
      for (int r = 0; r < 4; ++r) {
        float v = acc[fr][fc][r];
        if (rope) {
          const long row = rbase + fr * 16 + lhi * 4 + r;
          const int d = fc * 16 + l15;
          const float rot = (fc < 2) ? -acc[fr][fc + 2][r] : acc[fr][fc - 2][r];
          v = v * cosp[row * 64 + d] + rot * sinp[row * 64 + d];
        }
        *(float*)(eplds + (lhi * 4 + r) * 256 + (fc * 16 + l15) * 4) = v;
      }
    asm volatile("s_waitcnt lgkmcnt(0)" ::: "memory");
    #pragma unroll
    for (int tt = 0; tt < 4; ++tt) {
      const int r16 = tt * 4 + (lane >> 4);
      const f32x4 vv = *(const f32x4*)(eplds + r16 * 256 + (lane & 15) * 16);
      const long row = rbase + fr * 16 + r16;
      __builtin_nontemporal_store(vv,
          (f32x4*)(out + row * 6720 + colBase + (lane & 15) * 4));
    }
  };

  if (kpe) {
    if (wn == 0) {
      #pragma unroll
      for (int fr = 0; fr < 4; ++fr) storeT(fr, 6144, true);
    }
  } else if ((wcol % 192) == 128) {
    #pragma unroll
    for (int fr = 0; fr < 4; ++fr) storeT(fr, wcol, true);
  } else {
    #pragma unroll
    for (int fr = 0; fr < 4; ++fr) storeT(fr, wcol, false);
  }
}

// ---------------- launch ----------------

extern "C" void kernel_launch(void* const* d_in, const int* in_sizes, int n_in,
                              void* d_out, int out_size, void* d_ws, size_t ws_size,
                              hipStream_t stream) {
  const float* x    = (const float*)d_in[0];
  const float* cosp = (const float*)d_in[1];
  const float* sinp = (const float*)d_in[2];
  const float* Wqa  = (const float*)d_in[3];
  const float* Wqb  = (const float*)d_in[4];
  const float* Wkva = (const float*)d_in[5];
  float* out = (float*)d_out;

  char* ws = (char*)d_ws;
  __hip_bfloat16* xb  = (__hip_bfloat16*)ws;
  __hip_bfloat16* w1  = (__hip_bfloat16*)(ws + 67108864L);
  __hip_bfloat16* wqb = (__hip_bfloat16*)(ws + 67108864L + 17825792L);
  unsigned short* ql  = (unsigned short*)(ws + 67108864L + 17825792L + 18874368L);

  cvt_bf16_kernel<<<2048, 256, 0, stream>>>(x,   (unsigned short*)xb,  8192L * 4096 / 4);
  cvt_bf16_kernel<<<1024, 256, 0, stream>>>(Wqa, (unsigned short*)w1,  1536L * 4096 / 4);
  cvt_pad_kernel<<<640, 256, 0, stream>>>(Wkva, (unsigned short*)(w1 + 1536L * 4096),
                                          576L * 4096 / 4, 640L * 4096 / 4);
  cvt_bf16_kernel<<<1024, 256, 0, stream>>>(Wqb, (unsigned short*)wqb, 6144L * 1536 / 4);

  // Reference BOTH template instantiations (round-8 compile context, rule #19).
  (void)hipFuncSetAttribute((const void*)&mla_gemm<0>,
                            hipFuncAttributeMaxDynamicSharedMemorySize, 131072);
  (void)hipFuncSetAttribute((const void*)&mla_gemm<1>,
                            hipFuncAttributeMaxDynamicSharedMemorySize, 131072);
  (void)hipFuncSetAttribute((const void*)&mla_gemm2,
                            hipFuncAttributeMaxDynamicSharedMemorySize, 73728);

  // launch1: x @ w1[0:2048] -> q_lora + compressed_kv. 256 blocks (1 round).
  mla_gemm<0><<<dim3(256), 512, 131072, stream>>>(xb, w1, 4096, nullptr, nullptr,
                                                  ql, cosp, sinp, out);
  // launch2: 32 k_pe blocks (K=4096, LPT-first) + 1536 q blocks (K=1536),
  // 256x128 tiles, 2 blocks/CU, bn-major XCD locality.
  mla_gemm2<<<dim3(1568), 512, 73728, stream>>>((const __hip_bfloat16*)ql, wqb,
                                                xb, w1 + 2048L * 4096,
                                                cosp, sinp, out);
}

// Round 14
// 340.662 us; speedup vs baseline: 1.9866x; 1.0232x over previous
//
#include <hip/hip_runtime.h>
#include <hip/hip_bf16.h>
#include <stdint.h>

typedef __bf16 bf16x8 __attribute__((ext_vector_type(8)));
typedef float f32x4 __attribute__((ext_vector_type(4)));
typedef float fvec4 __attribute__((ext_vector_type(4)));
typedef unsigned short usvec4 __attribute__((ext_vector_type(4)));
typedef unsigned int ui32x4 __attribute__((ext_vector_type(4)));

#define AS3 __attribute__((address_space(3)))
#define AS1 __attribute__((address_space(1)))

static __device__ __forceinline__ unsigned short f2bf(float f) {
  unsigned int u = __float_as_uint(f);
  u += 0x7FFF + ((u >> 16) & 1);   // round-to-nearest-even
  return (unsigned short)(u >> 16);
}

// ---------------- fp32 -> bf16 conversion kernels ----------------

extern "C" __global__ void cvt_bf16_kernel(const float* __restrict__ src,
                                           unsigned short* __restrict__ dst,
                                           long n4) {
  long i = (long)blockIdx.x * blockDim.x + threadIdx.x;
  const long stride = (long)gridDim.x * blockDim.x;
  for (; i < n4; i += stride) {
    const fvec4 v = __builtin_nontemporal_load(&((const fvec4*)src)[i]);
    usvec4 o;
    o.x = f2bf(v.x); o.y = f2bf(v.y); o.z = f2bf(v.z); o.w = f2bf(v.w);
    ((usvec4*)dst)[i] = o;
  }
}

extern "C" __global__ void cvt_pad_kernel(const float* __restrict__ src,
                                          unsigned short* __restrict__ dst,
                                          long nsrc4, long ntot4) {
  long i = (long)blockIdx.x * blockDim.x + threadIdx.x;
  const long stride = (long)gridDim.x * blockDim.x;
  for (; i < ntot4; i += stride) {
    usvec4 o = {0, 0, 0, 0};
    if (i < nsrc4) {
      const fvec4 v = __builtin_nontemporal_load(&((const fvec4*)src)[i]);
      o.x = f2bf(v.x); o.y = f2bf(v.y); o.z = f2bf(v.z); o.w = f2bf(v.w);
    }
    ((usvec4*)dst)[i] = o;
  }
}

// ============ 256x256 bf16 NT GEMM (C = A * Bw^T), BK=64 ============
// EXACT round-8 build (best timed: 341.5 us), restored byte-identically.
// ONE barrier per phase (4/tile). Phase block:
//   { ds_reads(q); gload stages; [VMW(n)]; s_barrier; sched_barrier(0);
//     [lgkmcnt(0)+sched_barrier(0)]; 16 MFMA }
// Overwrite safety: a stage issued in phase p is safe to write region R iff
// R's last ds_reads were in phase <= p-2 (each wave's lgkmcnt(0) for phase
// p-2 precedes the barrier of phase p-1, which precedes the stage issue).
// Schedule (tile t, buf b=t&1): q0 reads A0,B0 -> mmac(0,0); q1 reads B1 ->
// mmac(0,1); q2 reads A1 -> mmac(1,1); q3 (regs only) -> mmac(1,0).
// Stages: q0: A1(t+1); q2: A0,B0(t+2); q3: B1(t+2).
// Counted vmcnt: steady VMW(10)@q0, VMW(8)@q1, VMW(10)@q3;
//   peel t=T-2: VMW(4)@q3; t=T-1: VMW(2)@q0, VMW(0)@q1.
// Swizzle: both-sides k16-chunk ^ row&7. Epilogue: LDS-transposed full-line.

#define VMW(N) asm volatile("s_waitcnt vmcnt(" #N ")" ::: "memory")
#define BAR() do { __builtin_amdgcn_s_barrier(); \
                   __builtin_amdgcn_sched_barrier(0); } while (0)
#define LGKM0() do { asm volatile("s_waitcnt lgkmcnt(0)" ::: "memory"); \
                     __builtin_amdgcn_sched_barrier(0); } while (0)

template <int MODE>
__global__ __launch_bounds__(512, 2)
void mla_gemm(const __hip_bfloat16* __restrict__ A0p,
              const __hip_bfloat16* __restrict__ B0p, int K0,
              const __hip_bfloat16* __restrict__ A1p,
              const __hip_bfloat16* __restrict__ B1p,
              unsigned short* __restrict__ qlora,
              const float* __restrict__ cosp,
              const float* __restrict__ sinp,
              float* __restrict__ out) {
  extern __shared__ __align__(128) char lds[];
  const int tid = threadIdx.x;
  const int lane = tid & 63;
  const int w = tid >> 6;
  const int wm = w >> 2, wn = w & 3;
  const int l15 = lane & 15, lhi = lane >> 4;
  const int srow8 = lane >> 3;
  const int swzc = ((lane & 7) ^ srow8) * 8;

  const __hip_bfloat16* Aptr;
  const __hip_bfloat16* Bptr;
  int K, bm, bn;
  bool isA2 = false;
  if constexpr (MODE == 0) {
    const int swz = ((int)blockIdx.x & 7) * 32 + ((int)blockIdx.x >> 3);
    bm = swz >> 3; bn = swz & 7;
    Aptr = A0p; Bptr = B0p; K = K0;
  } else {
    const int bid = (int)blockIdx.x;
    if (bid < 32) {
      isA2 = true; bm = bid; bn = 8; Aptr = A1p; Bptr = B1p; K = 4096;
    } else {
      const int b2 = bid - 32;
      const int swz = (b2 & 7) * 96 + (b2 >> 3);
      bm = swz / 24; bn = swz - bm * 24;
      Aptr = A0p; Bptr = B0p; K = K0;
    }
  }
  const long brow = (long)bm * 256;
  const int bcol = bn * 256;

  const __hip_bfloat16* aSt = Aptr + (brow + w * 16 + srow8) * (long)K + swzc;
  const __hip_bfloat16* bSt = Bptr + ((long)bcol + srow8) * (long)K + swzc;
  const int wj0 = w * 16, wj1 = w * 16 + 8;
  const int cb_j0 = (2 * (wj0 >> 5)) * 32 + (wj0 & 31);
  const int cb_j1 = (2 * (wj1 >> 5)) * 32 + (wj1 & 31);
  const int ldsWj = w * 2048;

  const int aRdRow = (wm * 64 + l15) * 128;
  const int bRdRow = (wn * 32 + l15) * 128;
  const int ck0 = (lhi ^ (l15 & 7)) * 16;

  f32x4 acc[8][4] = {};
  bf16x8 aF[4][2];
  bf16x8 bF[2][2][2];

  const int T = K >> 6;

  auto stage = [&](int u, int kt) {
    const int b = kt & 1;
    if (u < 2) {
      const int off = b * 32768 + u * 16384 + ldsWj;
      __builtin_amdgcn_global_load_lds((AS1 void*)(aSt + (long)(u * 128) * K + kt * 64),
                                       (AS3 void*)(lds + off), 16, 0, 0);
      __builtin_amdgcn_global_load_lds((AS1 void*)(aSt + (long)(u * 128 + 8) * K + kt * 64),
                                       (AS3 void*)(lds + off + 1024), 16, 0, 0);
    } else {
      const int h = u - 2;
      const int off = 65536 + b * 32768 + h * 16384 + ldsWj;
      __builtin_amdgcn_global_load_lds((AS1 void*)(bSt + (long)(cb_j0 + h * 32) * K + kt * 64),
                                       (AS3 void*)(lds + off), 16, 0, 0);
      __builtin_amdgcn_global_load_lds((AS1 void*)(bSt + (long)(cb_j1 + h * 32) * K + kt * 64),
                                       (AS3 void*)(lds + off + 1024), 16, 0, 0);
    }
  };
  auto readA = [&](int qh, int b) {
    const int base = b * 32768 + qh * 16384 + aRdRow;
    #pragma unroll
    for (int fr = 0; fr < 4; ++fr) {
      aF[fr][0] = *(const bf16x8*)(lds + base + fr * 2048 + ck0);
      aF[fr][1] = *(const bf16x8*)(lds + base + fr * 2048 + (ck0 ^ 64));
    }
  };
  auto readB = [&](int c, int b) {
    const int base = 65536 + b * 32768 + c * 16384 + bRdRow;
    #pragma unroll
    for (int fq = 0; fq < 2; ++fq) {
      bF[c][fq][0] = *(const bf16x8*)(lds + base + fq * 2048 + ck0);
      bF[c][fq][1] = *(const bf16x8*)(lds + base + fq * 2048 + (ck0 ^ 64));
    }
  };
  auto mmac = [&](int qh, int c) {
    __builtin_amdgcn_s_setprio(1);
    #pragma unroll
    for (int fr = 0; fr < 4; ++fr)
      #pragma unroll
      for (int fq = 0; fq < 2; ++fq) {
        acc[qh * 4 + fr][c * 2 + fq] = __builtin_amdgcn_mfma_f32_16x16x32_bf16(
            aF[fr][0], bF[c][fq][0], acc[qh * 4 + fr][c * 2 + fq], 0, 0, 0);
        acc[qh * 4 + fr][c * 2 + fq] = __builtin_amdgcn_mfma_f32_16x16x32_bf16(
            aF[fr][1], bF[c][fq][1], acc[qh * 4 + fr][c * 2 + fq], 0, 0, 0);
      }
    __builtin_amdgcn_s_setprio(0);
  };

  // prologue: tiles 0,1 in issue order A0B0 | B1 | A1 per tile
  stage(0, 0); stage(2, 0); stage(3, 0); stage(1, 0);
  stage(0, 1); stage(2, 1); stage(3, 1); stage(1, 1);
  VMW(12);   // tile0 A0,B0 landed
  BAR();

  for (int t = 0; t < T - 2; ++t) {
    const int b = t & 1;
    // q0
    readA(0, b); readB(0, b); if (t) stage(1, t + 1);
    VMW(10); BAR(); LGKM0(); mmac(0, 0);
    // q1
    readB(1, b);
    VMW(8); BAR(); LGKM0(); mmac(0, 1);
    // q2
    readA(1, b); stage(0, t + 2); stage(2, t + 2);
    BAR(); LGKM0(); mmac(1, 1);
    // q3 (registers only)
    stage(3, t + 2);
    VMW(10); BAR(); mmac(1, 0);
  }
  {  // t = T-2 (exact drain counts)
    const int b = (T - 2) & 1;
    readA(0, b); readB(0, b); stage(1, T - 1);
    VMW(10); BAR(); LGKM0(); mmac(0, 0);
    readB(1, b);
    VMW(8); BAR(); LGKM0(); mmac(0, 1);
    readA(1, b);
    BAR(); LGKM0(); mmac(1, 1);
    VMW(4); BAR(); mmac(1, 0);
  }
  {  // t = T-1
    const int b = (T - 1) & 1;
    readA(0, b); readB(0, b);
    VMW(2); BAR(); LGKM0(); mmac(0, 0);
    readB(1, b);
    VMW(0); BAR(); LGKM0(); mmac(0, 1);
    readA(1, b);
    BAR(); LGKM0(); mmac(1, 1);
    BAR(); mmac(1, 0);
  }

  // ---- epilogue: LDS-transposed FULL-LINE stores ----
  // acc value (i8,j,r): row = brow + (i8>>2)*128 + wm*64 + (i8&3)*16 + lhi*4 + r,
  //                     col = bcol + wn*64 + (j>>1)*32 + (j&1)*16 + l15.
  // Each wave transposes its 16x64 tile through its own 4KB LDS (wave-local,
  // lgkmcnt(0) only), then stores f32x4 per lane: 4 rows x 256B full lines.
  const int wcol = bcol + wn * 64;
  const long rbase = brow + wm * 64;
  char* eplds = lds + w * 4096;

  auto storeTileF32 = [&](int i8, float* dst, bool rope) {
    #pragma unroll
    for (int j = 0; j < 4; ++j)
      #pragma unroll
      for (int r = 0; r < 4; ++r) {
        float v = acc[i8][j][r];
        if (rope) {
          const long row = rbase + (i8 >> 2) * 128 + (i8 & 3) * 16 + lhi * 4 + r;
          const int d = (j >> 1) * 32 + (j & 1) * 16 + l15;
          const float rot = (j < 2) ? -acc[i8][j + 2][r] : acc[i8][j - 2][r];
          v = v * cosp[row * 64 + d] + rot * sinp[row * 64 + d];
        }
        *(float*)(eplds + (lhi * 4 + r) * 256 + ((j >> 1) * 32 + (j & 1) * 16 + l15) * 4) = v;
      }
    asm volatile("s_waitcnt lgkmcnt(0)" ::: "memory");
    #pragma unroll
    for (int t = 0; t < 4; ++t) {
      const int r16 = t * 4 + (lane >> 4);
      const f32x4 v = *(const f32x4*)(eplds + r16 * 256 + (lane & 15) * 16);
      const long row = rbase + (i8 >> 2) * 128 + (i8 & 3) * 16 + r16;
      __builtin_nontemporal_store(v, (f32x4*)(dst + row * 6720 + (lane & 15) * 4));
    }
  };
  auto storeTileBf16 = [&](int i8) {
    #pragma unroll
    for (int j = 0; j < 4; ++j)
      #pragma unroll
      for (int r = 0; r < 4; ++r)
        *(unsigned short*)(eplds + (lhi * 4 + r) * 128 +
                           ((j >> 1) * 32 + (j & 1) * 16 + l15) * 2) = f2bf(acc[i8][j][r]);
    asm volatile("s_waitcnt lgkmcnt(0)" ::: "memory");
    #pragma unroll
    for (int t = 0; t < 2; ++t) {
      const int r16 = t * 8 + (lane >> 3);
      const ui32x4 v = *(const ui32x4*)(eplds + r16 * 128 + (lane & 7) * 16);
      const long row = rbase + (i8 >> 2) * 128 + (i8 & 3) * 16 + r16;
      *(ui32x4*)((char*)qlora + (row * 1536 + wcol) * 2 + (lane & 7) * 16) = v;
    }
  };

  if constexpr (MODE == 0) {
    if (wcol < 1536) {          // q_lora bf16 (cached; re-read by launch2)
      #pragma unroll
      for (int i8 = 0; i8 < 8; ++i8) storeTileBf16(i8);
    } else {                    // compressed_kv -> out cols 6208..6719
      #pragma unroll
      for (int i8 = 0; i8 < 8; ++i8) storeTileF32(i8, out + wcol + 4672, false);
    }
  } else {
    if (isA2) {
      if (wn == 0) {            // k_pe + RoPE -> out cols 6144..6207
        #pragma unroll
        for (int i8 = 0; i8 < 8; ++i8) storeTileF32(i8, out + 6144, true);
      }                         // wn 1..3: pad cols, dropped
    } else if ((wcol % 192) != 128) {  // q_nope
      #pragma unroll
      for (int i8 = 0; i8 < 8; ++i8) storeTileF32(i8, out + wcol, false);
    } else {                    // q_pe 64-block + RoPE
      #pragma unroll
      for (int i8 = 0; i8 < 8; ++i8) storeTileF32(i8, out + wcol, true);
    }
  }
}

// ---------------- launch ----------------

extern "C" void kernel_launch(void* const* d_in, const int* in_sizes, int n_in,
                              void* d_out, int out_size, void* d_ws, size_t ws_size,
                              hipStream_t stream) {
  const float* x    = (const float*)d_in[0];
  const float* cosp = (const float*)d_in[1];
  const float* sinp = (const float*)d_in[2];
  const float* Wqa  = (const float*)d_in[3];
  const float* Wqb  = (const float*)d_in[4];
  const float* Wkva = (const float*)d_in[5];
  float* out = (float*)d_out;

  char* ws = (char*)d_ws;
  __hip_bfloat16* xb  = (__hip_bfloat16*)ws;
  __hip_bfloat16* w1  = (__hip_bfloat16*)(ws + 67108864L);
  __hip_bfloat16* wqb = (__hip_bfloat16*)(ws + 67108864L + 17825792L);
  unsigned short* ql  = (unsigned short*)(ws + 67108864L + 17825792L + 18874368L);

  cvt_bf16_kernel<<<2048, 256, 0, stream>>>(x,   (unsigned short*)xb,  8192L * 4096 / 4);
  cvt_bf16_kernel<<<1024, 256, 0, stream>>>(Wqa, (unsigned short*)w1,  1536L * 4096 / 4);
  cvt_pad_kernel<<<640, 256, 0, stream>>>(Wkva, (unsigned short*)(w1 + 1536L * 4096),
                                          576L * 4096 / 4, 640L * 4096 / 4);
  cvt_bf16_kernel<<<1024, 256, 0, stream>>>(Wqb, (unsigned short*)wqb, 6144L * 1536 / 4);

  (void)hipFuncSetAttribute((const void*)&mla_gemm<0>,
                            hipFuncAttributeMaxDynamicSharedMemorySize, 131072);
  (void)hipFuncSetAttribute((const void*)&mla_gemm<1>,
                            hipFuncAttributeMaxDynamicSharedMemorySize, 131072);

  // launch1: x @ w1[0:2048] -> q_lora + compressed_kv. 256 blocks (1 round).
  mla_gemm<0><<<dim3(256), 512, 131072, stream>>>(xb, w1, 4096, nullptr, nullptr,
                                                  ql, cosp, sinp, out);
  // launch2: 32 k_pe blocks (K=4096, LPT-first) + 768 q blocks (K=1536).
  mla_gemm<1><<<dim3(800), 512, 131072, stream>>>((const __hip_bfloat16*)ql, wqb, 1536,
                                                  xb, w1, ql, cosp, sinp, out);
}

// Round 15
// 331.579 us; speedup vs baseline: 2.0410x; 1.0274x over previous
//
#include <hip/hip_runtime.h>
#include <hip/hip_bf16.h>
#include <stdint.h>

typedef __bf16 bf16x8 __attribute__((ext_vector_type(8)));
typedef float f32x4 __attribute__((ext_vector_type(4)));
typedef float fvec4 __attribute__((ext_vector_type(4)));
typedef unsigned short usvec4 __attribute__((ext_vector_type(4)));
typedef unsigned int ui32x4 __attribute__((ext_vector_type(4)));

#define AS3 __attribute__((address_space(3)))
#define AS1 __attribute__((address_space(1)))

static __device__ __forceinline__ unsigned short f2bf(float f) {
  unsigned int u = __float_as_uint(f);
  u += 0x7FFF + ((u >> 16) & 1);   // round-to-nearest-even
  return (unsigned short)(u >> 16);
}

// ---------------- fp32 -> bf16 conversion kernels ----------------

extern "C" __global__ void cvt_bf16_kernel(const float* __restrict__ src,
                                           unsigned short* __restrict__ dst,
                                           long n4) {
  long i = (long)blockIdx.x * blockDim.x + threadIdx.x;
  const long stride = (long)gridDim.x * blockDim.x;
  for (; i < n4; i += stride) {
    const fvec4 v = __builtin_nontemporal_load(&((const fvec4*)src)[i]);
    usvec4 o;
    o.x = f2bf(v.x); o.y = f2bf(v.y); o.z = f2bf(v.z); o.w = f2bf(v.w);
    ((usvec4*)dst)[i] = o;
  }
}

extern "C" __global__ void cvt_pad_kernel(const float* __restrict__ src,
                                          unsigned short* __restrict__ dst,
                                          long nsrc4, long ntot4) {
  long i = (long)blockIdx.x * blockDim.x + threadIdx.x;
  const long stride = (long)gridDim.x * blockDim.x;
  for (; i < ntot4; i += stride) {
    usvec4 o = {0, 0, 0, 0};
    if (i < nsrc4) {
      const fvec4 v = __builtin_nontemporal_load(&((const fvec4*)src)[i]);
      o.x = f2bf(v.x); o.y = f2bf(v.y); o.z = f2bf(v.z); o.w = f2bf(v.w);
    }
    ((usvec4*)dst)[i] = o;
  }
}

// ---------------- k_pe split-K reduce + RoPE ----------------
// part[ks][row][d], ks<8, row<8192, d<64. s = sum_ks; RoPE pairing d <-> d+-32.

extern "C" __global__ void kpe_reduce_kernel(const float* __restrict__ part,
                                             const float* __restrict__ cosp,
                                             const float* __restrict__ sinp,
                                             float* __restrict__ out) {
  const int idx = (int)blockIdx.x * 256 + threadIdx.x;   // 0..524287
  const int row = idx >> 6, d = idx & 63;
  const int pidx = (idx - d) + ((d < 32) ? d + 32 : d - 32);
  float s = 0.f, sp = 0.f;
  #pragma unroll
  for (int ks = 0; ks < 8; ++ks) {
    s  += part[(long)ks * 524288 + idx];
    sp += part[(long)ks * 524288 + pidx];
  }
  const float rot = (d < 32) ? -sp : sp;
  out[(long)row * 6720 + 6144 + d] =
      s * cosp[(long)row * 64 + d] + rot * sinp[(long)row * 64 + d];
}

// ============ 256x256 bf16 NT GEMM (C = A * Bw^T), BK=64 ============
// Round-8 proven K-loop (4 barriers/tile, counted vmcnt, both-sides swizzle),
// unchanged. Round-15 change is ONLY the MODE-1 block mapping:
//   bid 0..767   : q blocks (exact 3 rounds of 256)
//   bid 768..1023: k_pe split-K blocks (bm=(bid-768)>>3, ks=(bid-768)&7,
//                  K-window [ks*512,(ks+1)*512), T=8) writing PARTIALS
//                  (no RoPE) to kpart; summed+RoPE'd by kpe_reduce_kernel.

#define VMW(N) asm volatile("s_waitcnt vmcnt(" #N ")" ::: "memory")
#define BAR() do { __builtin_amdgcn_s_barrier(); \
                   __builtin_amdgcn_sched_barrier(0); } while (0)
#define LGKM0() do { asm volatile("s_waitcnt lgkmcnt(0)" ::: "memory"); \
                     __builtin_amdgcn_sched_barrier(0); } while (0)

template <int MODE>
__global__ __launch_bounds__(512, 2)
void mla_gemm(const __hip_bfloat16* __restrict__ A0p,
              const __hip_bfloat16* __restrict__ B0p, int K0,
              const __hip_bfloat16* __restrict__ A1p,
              const __hip_bfloat16* __restrict__ B1p,
              float* __restrict__ kpart,
              unsigned short* __restrict__ qlora,
              const float* __restrict__ cosp,
              const float* __restrict__ sinp,
              float* __restrict__ out) {
  extern __shared__ __align__(128) char lds[];
  const int tid = threadIdx.x;
  const int lane = tid & 63;
  const int w = tid >> 6;
  const int wm = w >> 2, wn = w & 3;
  const int l15 = lane & 15, lhi = lane >> 4;
  const int srow8 = lane >> 3;
  const int swzc = ((lane & 7) ^ srow8) * 8;

  const __hip_bfloat16* Aptr;
  const __hip_bfloat16* Bptr;
  int K, bm, bn, T, koff = 0, ks = 0;
  bool isA2 = false;
  if constexpr (MODE == 0) {
    const int swz = ((int)blockIdx.x & 7) * 32 + ((int)blockIdx.x >> 3);
    bm = swz >> 3; bn = swz & 7;
    Aptr = A0p; Bptr = B0p; K = K0; T = K0 >> 6;
  } else {
    const int bid = (int)blockIdx.x;
    if (bid >= 768) {  // k_pe split-K: rows of x, w1 cols 2048.., K-window 512
      isA2 = true;
      bm = (bid - 768) >> 3; bn = 8; ks = (bid - 768) & 7;
      Aptr = A1p; Bptr = B1p; K = 4096; T = 8; koff = ks * 512;
    } else {
      const int b2 = bid;
      const int swz = (b2 & 7) * 96 + (b2 >> 3);
      bm = swz / 24; bn = swz - bm * 24;
      Aptr = A0p; Bptr = B0p; K = K0; T = K0 >> 6;
    }
  }
  const long brow = (long)bm * 256;
  const int bcol = bn * 256;

  const __hip_bfloat16* aSt = Aptr + (brow + w * 16 + srow8) * (long)K + swzc + koff;
  const __hip_bfloat16* bSt = Bptr + ((long)bcol + srow8) * (long)K + swzc + koff;
  const int wj0 = w * 16, wj1 = w * 16 + 8;
  const int cb_j0 = (2 * (wj0 >> 5)) * 32 + (wj0 & 31);
  const int cb_j1 = (2 * (wj1 >> 5)) * 32 + (wj1 & 31);
  const int ldsWj = w * 2048;

  const int aRdRow = (wm * 64 + l15) * 128;
  const int bRdRow = (wn * 32 + l15) * 128;
  const int ck0 = (lhi ^ (l15 & 7)) * 16;

  f32x4 acc[8][4] = {};
  bf16x8 aF[4][2];
  bf16x8 bF[2][2][2];

  auto stage = [&](int u, int kt) {
    const int b = kt & 1;
    if (u < 2) {
      const int off = b * 32768 + u * 16384 + ldsWj;
      __builtin_amdgcn_global_load_lds((AS1 void*)(aSt + (long)(u * 128) * K + kt * 64),
                                       (AS3 void*)(lds + off), 16, 0, 0);
      __builtin_amdgcn_global_load_lds((AS1 void*)(aSt + (long)(u * 128 + 8) * K + kt * 64),
                                       (AS3 void*)(lds + off + 1024), 16, 0, 0);
    } else {
      const int h = u - 2;
      const int off = 65536 + b * 32768 + h * 16384 + ldsWj;
      __builtin_amdgcn_global_load_lds((AS1 void*)(bSt + (long)(cb_j0 + h * 32) * K + kt * 64),
                                       (AS3 void*)(lds + off), 16, 0, 0);
      __builtin_amdgcn_global_load_lds((AS1 void*)(bSt + (long)(cb_j1 + h * 32) * K + kt * 64),
                                       (AS3 void*)(lds + off + 1024), 16, 0, 0);
    }
  };
  auto readA = [&](int qh, int b) {
    const int base = b * 32768 + qh * 16384 + aRdRow;
    #pragma unroll
    for (int fr = 0; fr < 4; ++fr) {
      aF[fr][0] = *(const bf16x8*)(lds + base + fr * 2048 + ck0);
      aF[fr][1] = *(const bf16x8*)(lds + base + fr * 2048 + (ck0 ^ 64));
    }
  };
  auto readB = [&](int c, int b) {
    const int base = 65536 + b * 32768 + c * 16384 + bRdRow;
    #pragma unroll
    for (int fq = 0; fq < 2; ++fq) {
      bF[c][fq][0] = *(const bf16x8*)(lds + base + fq * 2048 + ck0);
      bF[c][fq][1] = *(const bf16x8*)(lds + base + fq * 2048 + (ck0 ^ 64));
    }
  };
  auto mmac = [&](int qh, int c) {
    __builtin_amdgcn_s_setprio(1);
    #pragma unroll
    for (int fr = 0; fr < 4; ++fr)
      #pragma unroll
      for (int fq = 0; fq < 2; ++fq) {
        acc[qh * 4 + fr][c * 2 + fq] = __builtin_amdgcn_mfma_f32_16x16x32_bf16(
            aF[fr][0], bF[c][fq][0], acc[qh * 4 + fr][c * 2 + fq], 0, 0, 0);
        acc[qh * 4 + fr][c * 2 + fq] = __builtin_amdgcn_mfma_f32_16x16x32_bf16(
            aF[fr][1], bF[c][fq][1], acc[qh * 4 + fr][c * 2 + fq], 0, 0, 0);
      }
    __builtin_amdgcn_s_setprio(0);
  };

  // prologue: tiles 0,1 in issue order A0B0 | B1 | A1 per tile
  stage(0, 0); stage(2, 0); stage(3, 0); stage(1, 0);
  stage(0, 1); stage(2, 1); stage(3, 1); stage(1, 1);
  VMW(12);   // tile0 A0,B0 landed
  BAR();

  for (int t = 0; t < T - 2; ++t) {
    const int b = t & 1;
    // q0
    readA(0, b); readB(0, b); if (t) stage(1, t + 1);
    VMW(10); BAR(); LGKM0(); mmac(0, 0);
    // q1
    readB(1, b);
    VMW(8); BAR(); LGKM0(); mmac(0, 1);
    // q2
    readA(1, b); stage(0, t + 2); stage(2, t + 2);
    BAR(); LGKM0(); mmac(1, 1);
    // q3 (registers only)
    stage(3, t + 2);
    VMW(10); BAR(); mmac(1, 0);
  }
  {  // t = T-2 (exact drain counts)
    const int b = (T - 2) & 1;
    readA(0, b); readB(0, b); stage(1, T - 1);
    VMW(10); BAR(); LGKM0(); mmac(0, 0);
    readB(1, b);
    VMW(8); BAR(); LGKM0(); mmac(0, 1);
    readA(1, b);
    BAR(); LGKM0(); mmac(1, 1);
    VMW(4); BAR(); mmac(1, 0);
  }
  {  // t = T-1
    const int b = (T - 1) & 1;
    readA(0, b); readB(0, b);
    VMW(2); BAR(); LGKM0(); mmac(0, 0);
    readB(1, b);
    VMW(0); BAR(); LGKM0(); mmac(0, 1);
    readA(1, b);
    BAR(); LGKM0(); mmac(1, 1);
    BAR(); mmac(1, 0);
  }

  // ---- epilogue ----
  // acc value (i8,j,r): row = brow + (i8>>2)*128 + wm*64 + (i8&3)*16 + lhi*4 + r,
  //                     col = bcol + wn*64 + (j>>1)*32 + (j&1)*16 + l15.
  const int wcol = bcol + wn * 64;
  const long rbase = brow + wm * 64;
  char* eplds = lds + w * 4096;

  auto storeTileF32 = [&](int i8, float* dst, bool rope) {
    #pragma unroll
    for (int j = 0; j < 4; ++j)
      #pragma unroll
      for (int r = 0; r < 4; ++r) {
        float v = acc[i8][j][r];
        if (rope) {
          const long row = rbase + (i8 >> 2) * 128 + (i8 & 3) * 16 + lhi * 4 + r;
          const int d = (j >> 1) * 32 + (j & 1) * 16 + l15;
          const float rot = (j < 2) ? -acc[i8][j + 2][r] : acc[i8][j - 2][r];
          v = v * cosp[row * 64 + d] + rot * sinp[row * 64 + d];
        }
        *(float*)(eplds + (lhi * 4 + r) * 256 + ((j >> 1) * 32 + (j & 1) * 16 + l15) * 4) = v;
      }
    asm volatile("s_waitcnt lgkmcnt(0)" ::: "memory");
    #pragma unroll
    for (int t = 0; t < 4; ++t) {
      const int r16 = t * 4 + (lane >> 4);
      const f32x4 v = *(const f32x4*)(eplds + r16 * 256 + (lane & 15) * 16);
      const long row = rbase + (i8 >> 2) * 128 + (i8 & 3) * 16 + r16;
      __builtin_nontemporal_store(v, (f32x4*)(dst + row * 6720 + (lane & 15) * 4));
    }
  };
  auto storeTileBf16 = [&](int i8) {
    #pragma unroll
    for (int j = 0; j < 4; ++j)
      #pragma unroll
      for (int r = 0; r < 4; ++r)
        *(unsigned short*)(eplds + (lhi * 4 + r) * 128 +
                           ((j >> 1) * 32 + (j & 1) * 16 + l15) * 2) = f2bf(acc[i8][j][r]);
    asm volatile("s_waitcnt lgkmcnt(0)" ::: "memory");
    #pragma unroll
    for (int t = 0; t < 2; ++t) {
      const int r16 = t * 8 + (lane >> 3);
      const ui32x4 v = *(const ui32x4*)(eplds + r16 * 128 + (lane & 7) * 16);
      const long row = rbase + (i8 >> 2) * 128 + (i8 & 3) * 16 + r16;
      *(ui32x4*)((char*)qlora + (row * 1536 + wcol) * 2 + (lane & 7) * 16) = v;
    }
  };

  if constexpr (MODE == 0) {
    if (wcol < 1536) {          // q_lora bf16 (cached; re-read by launch2)
      #pragma unroll
      for (int i8 = 0; i8 < 8; ++i8) storeTileBf16(i8);
    } else {                    // compressed_kv -> out cols 6208..6719
      #pragma unroll
      for (int i8 = 0; i8 < 8; ++i8) storeTileF32(i8, out + wcol + 4672, false);
    }
  } else {
    if (isA2) {
      if (wn == 0) {            // k_pe split-K PARTIAL (no RoPE) -> kpart[ks]
        float* pp = kpart + (long)ks * 524288;
        #pragma unroll
        for (int i8 = 0; i8 < 8; ++i8)
          #pragma unroll
          for (int j = 0; j < 4; ++j)
            #pragma unroll
            for (int r = 0; r < 4; ++r) {
              const long row = rbase + (i8 >> 2) * 128 + (i8 & 3) * 16 + lhi * 4 + r;
              const int d = (j >> 1) * 32 + (j & 1) * 16 + l15;
              pp[row * 64 + d] = acc[i8][j][r];
            }
      }                         // wn 1..3: pad cols, dropped
    } else if ((wcol % 192) != 128) {  // q_nope
      #pragma unroll
      for (int i8 = 0; i8 < 8; ++i8) storeTileF32(i8, out + wcol, false);
    } else {                    // q_pe 64-block + RoPE
      #pragma unroll
      for (int i8 = 0; i8 < 8; ++i8) storeTileF32(i8, out + wcol, true);
    }
  }
}

// ---------------- launch ----------------

extern "C" void kernel_launch(void* const* d_in, const int* in_sizes, int n_in,
                              void* d_out, int out_size, void* d_ws, size_t ws_size,
                              hipStream_t stream) {
  const float* x    = (const float*)d_in[0];
  const float* cosp = (const float*)d_in[1];
  const float* sinp = (const float*)d_in[2];
  const float* Wqa  = (const float*)d_in[3];
  const float* Wqb  = (const float*)d_in[4];
  const float* Wkva = (const float*)d_in[5];
  float* out = (float*)d_out;

  char* ws = (char*)d_ws;
  // ws: xb 64MB | w1 17MB | wqb 18MB | ql 24MB | kpart 16MB (total ~139MB)
  __hip_bfloat16* xb  = (__hip_bfloat16*)ws;
  __hip_bfloat16* w1  = (__hip_bfloat16*)(ws + 67108864L);
  __hip_bfloat16* wqb = (__hip_bfloat16*)(ws + 67108864L + 17825792L);
  unsigned short* ql  = (unsigned short*)(ws + 67108864L + 17825792L + 18874368L);
  float* kpart        = (float*)(ws + 67108864L + 17825792L + 18874368L + 25165824L);

  cvt_bf16_kernel<<<2048, 256, 0, stream>>>(x,   (unsigned short*)xb,  8192L * 4096 / 4);
  cvt_bf16_kernel<<<1024, 256, 0, stream>>>(Wqa, (unsigned short*)w1,  1536L * 4096 / 4);
  cvt_pad_kernel<<<640, 256, 0, stream>>>(Wkva, (unsigned short*)(w1 + 1536L * 4096),
                                          576L * 4096 / 4, 640L * 4096 / 4);
  cvt_bf16_kernel<<<1024, 256, 0, stream>>>(Wqb, (unsigned short*)wqb, 6144L * 1536 / 4);

  (void)hipFuncSetAttribute((const void*)&mla_gemm<0>,
                            hipFuncAttributeMaxDynamicSharedMemorySize, 131072);
  (void)hipFuncSetAttribute((const void*)&mla_gemm<1>,
                            hipFuncAttributeMaxDynamicSharedMemorySize, 131072);

  // launch1: x @ w1[0:2048] -> q_lora + compressed_kv. 256 blocks (1 round).
  mla_gemm<0><<<dim3(256), 512, 131072, stream>>>(xb, w1, 4096, nullptr, nullptr,
                                                  nullptr, ql, cosp, sinp, out);
  // launch2: 768 q blocks (exact 3 rounds) + 256 k_pe split-K blocks (T=8).
  mla_gemm<1><<<dim3(1024), 512, 131072, stream>>>((const __hip_bfloat16*)ql, wqb, 1536,
                                                   xb, w1, kpart, ql, cosp, sinp, out);
  // reduce k_pe partials + RoPE -> out cols 6144..6207.
  kpe_reduce_kernel<<<dim3(2048), 256, 0, stream>>>(kpart, cosp, sinp, out);
}

// Round 16
// 330.095 us; speedup vs baseline: 2.0502x; 1.0045x over previous
//
#include <hip/hip_runtime.h>
#include <hip/hip_bf16.h>
#include <stdint.h>

typedef __bf16 bf16x8 __attribute__((ext_vector_type(8)));
typedef float f32x4 __attribute__((ext_vector_type(4)));
typedef float fvec4 __attribute__((ext_vector_type(4)));
typedef unsigned short usvec4 __attribute__((ext_vector_type(4)));
typedef unsigned int ui32x4 __attribute__((ext_vector_type(4)));

#define AS3 __attribute__((address_space(3)))
#define AS1 __attribute__((address_space(1)))

static __device__ __forceinline__ unsigned short f2bf(float f) {
  unsigned int u = __float_as_uint(f);
  u += 0x7FFF + ((u >> 16) & 1);   // round-to-nearest-even
  return (unsigned short)(u >> 16);
}

// ---------------- fp32 -> bf16 conversion kernels ----------------

extern "C" __global__ void cvt_bf16_kernel(const float* __restrict__ src,
                                           unsigned short* __restrict__ dst,
                                           long n4) {
  long i = (long)blockIdx.x * blockDim.x + threadIdx.x;
  const long stride = (long)gridDim.x * blockDim.x;
  for (; i < n4; i += stride) {
    const fvec4 v = __builtin_nontemporal_load(&((const fvec4*)src)[i]);
    usvec4 o;
    o.x = f2bf(v.x); o.y = f2bf(v.y); o.z = f2bf(v.z); o.w = f2bf(v.w);
    ((usvec4*)dst)[i] = o;
  }
}

extern "C" __global__ void cvt_pad_kernel(const float* __restrict__ src,
                                          unsigned short* __restrict__ dst,
                                          long nsrc4, long ntot4) {
  long i = (long)blockIdx.x * blockDim.x + threadIdx.x;
  const long stride = (long)gridDim.x * blockDim.x;
  for (; i < ntot4; i += stride) {
    usvec4 o = {0, 0, 0, 0};
    if (i < nsrc4) {
      const fvec4 v = __builtin_nontemporal_load(&((const fvec4*)src)[i]);
      o.x = f2bf(v.x); o.y = f2bf(v.y); o.z = f2bf(v.z); o.w = f2bf(v.w);
    }
    ((usvec4*)dst)[i] = o;
  }
}

// ---------------- k_pe split-K reduce + RoPE ----------------
// part[ks][row][d], ks<8, row<8192, d<64. s = sum_ks; RoPE pairing d <-> d+-32.

extern "C" __global__ void kpe_reduce_kernel(const float* __restrict__ part,
                                             const float* __restrict__ cosp,
                                             const float* __restrict__ sinp,
                                             float* __restrict__ out) {
  const int idx = (int)blockIdx.x * 256 + threadIdx.x;   // 0..524287
  const int row = idx >> 6, d = idx & 63;
  const int pidx = (idx - d) + ((d < 32) ? d + 32 : d - 32);
  float s = 0.f, sp = 0.f;
  #pragma unroll
  for (int ks = 0; ks < 8; ++ks) {
    s  += part[(long)ks * 524288 + idx];
    sp += part[(long)ks * 524288 + pidx];
  }
  const float rot = (d < 32) ? -sp : sp;
  out[(long)row * 6720 + 6144 + d] =
      s * cosp[(long)row * 64 + d] + rot * sinp[(long)row * 64 + d];
}

// ============ 256x256 bf16 NT GEMM (C = A * Bw^T), BK=64 ============
// Round-8 proven K-loop (4 barriers/tile, counted vmcnt, both-sides swizzle),
// unchanged. Round-16 change is ONLY the MODE-1 q-block mapping:
//   bn-major per XCD: XCD x owns bn in {3x,3x+1,3x+2} (3 B-panels = 2.3MB,
//   L2-resident for the whole kernel); bm streams. Fixes the B re-fetch from
//   HBM (FETCH 297MB ~= 3x wqb) that exposed HBM latency at 1 block/CU.
//   bid 0..767   : q blocks (exact 3 rounds of 256)
//   bid 768..1023: k_pe split-K blocks (T=8, partials -> kpart, reduce kernel)

#define VMW(N) asm volatile("s_waitcnt vmcnt(" #N ")" ::: "memory")
#define BAR() do { __builtin_amdgcn_s_barrier(); \
                   __builtin_amdgcn_sched_barrier(0); } while (0)
#define LGKM0() do { asm volatile("s_waitcnt lgkmcnt(0)" ::: "memory"); \
                     __builtin_amdgcn_sched_barrier(0); } while (0)

template <int MODE>
__global__ __launch_bounds__(512, 2)
void mla_gemm(const __hip_bfloat16* __restrict__ A0p,
              const __hip_bfloat16* __restrict__ B0p, int K0,
              const __hip_bfloat16* __restrict__ A1p,
              const __hip_bfloat16* __restrict__ B1p,
              float* __restrict__ kpart,
              unsigned short* __restrict__ qlora,
              const float* __restrict__ cosp,
              const float* __restrict__ sinp,
              float* __restrict__ out) {
  extern __shared__ __align__(128) char lds[];
  const int tid = threadIdx.x;
  const int lane = tid & 63;
  const int w = tid >> 6;
  const int wm = w >> 2, wn = w & 3;
  const int l15 = lane & 15, lhi = lane >> 4;
  const int srow8 = lane >> 3;
  const int swzc = ((lane & 7) ^ srow8) * 8;

  const __hip_bfloat16* Aptr;
  const __hip_bfloat16* Bptr;
  int K, bm, bn, T, koff = 0, ks = 0;
  bool isA2 = false;
  if constexpr (MODE == 0) {
    const int swz = ((int)blockIdx.x & 7) * 32 + ((int)blockIdx.x >> 3);
    bm = swz >> 3; bn = swz & 7;
    Aptr = A0p; Bptr = B0p; K = K0; T = K0 >> 6;
  } else {
    const int bid = (int)blockIdx.x;
    if (bid >= 768) {  // k_pe split-K: rows of x, w1 cols 2048.., K-window 512
      isA2 = true;
      bm = (bid - 768) >> 3; bn = 8; ks = (bid - 768) & 7;
      Aptr = A1p; Bptr = B1p; K = 4096; T = 8; koff = ks * 512;
    } else {
      const int b2 = bid;
      const int x = b2 & 7;          // XCD id
      const int i = b2 >> 3;         // 0..95 within XCD
      bm = i / 3;                    // streams 0..31
      bn = x * 3 + (i % 3);          // XCD x owns B col-panels {3x..3x+2}
      Aptr = A0p; Bptr = B0p; K = K0; T = K0 >> 6;
    }
  }
  const long brow = (long)bm * 256;
  const int bcol = bn * 256;

  const __hip_bfloat16* aSt = Aptr + (brow + w * 16 + srow8) * (long)K + swzc + koff;
  const __hip_bfloat16* bSt = Bptr + ((long)bcol + srow8) * (long)K + swzc + koff;
  const int wj0 = w * 16, wj1 = w * 16 + 8;
  const int cb_j0 = (2 * (wj0 >> 5)) * 32 + (wj0 & 31);
  const int cb_j1 = (2 * (wj1 >> 5)) * 32 + (wj1 & 31);
  const int ldsWj = w * 2048;

  const int aRdRow = (wm * 64 + l15) * 128;
  const int bRdRow = (wn * 32 + l15) * 128;
  const int ck0 = (lhi ^ (l15 & 7)) * 16;

  f32x4 acc[8][4] = {};
  bf16x8 aF[4][2];
  bf16x8 bF[2][2][2];

  auto stage = [&](int u, int kt) {
    const int b = kt & 1;
    if (u < 2) {
      const int off = b * 32768 + u * 16384 + ldsWj;
      __builtin_amdgcn_global_load_lds((AS1 void*)(aSt + (long)(u * 128) * K + kt * 64),
                                       (AS3 void*)(lds + off), 16, 0, 0);
      __builtin_amdgcn_global_load_lds((AS1 void*)(aSt + (long)(u * 128 + 8) * K + kt * 64),
                                       (AS3 void*)(lds + off + 1024), 16, 0, 0);
    } else {
      const int h = u - 2;
      const int off = 65536 + b * 32768 + h * 16384 + ldsWj;
      __builtin_amdgcn_global_load_lds((AS1 void*)(bSt + (long)(cb_j0 + h * 32) * K + kt * 64),
                                       (AS3 void*)(lds + off), 16, 0, 0);
      __builtin_amdgcn_global_load_lds((AS1 void*)(bSt + (long)(cb_j1 + h * 32) * K + kt * 64),
                                       (AS3 void*)(lds + off + 1024), 16, 0, 0);
    }
  };
  auto readA = [&](int qh, int b) {
    const int base = b * 32768 + qh * 16384 + aRdRow;
    #pragma unroll
    for (int fr = 0; fr < 4; ++fr) {
      aF[fr][0] = *(const bf16x8*)(lds + base + fr * 2048 + ck0);
      aF[fr][1] = *(const bf16x8*)(lds + base + fr * 2048 + (ck0 ^ 64));
    }
  };
  auto readB = [&](int c, int b) {
    const int base = 65536 + b * 32768 + c * 16384 + bRdRow;
    #pragma unroll
    for (int fq = 0; fq < 2; ++fq) {
      bF[c][fq][0] = *(const bf16x8*)(lds + base + fq * 2048 + ck0);
      bF[c][fq][1] = *(const bf16x8*)(lds + base + fq * 2048 + (ck0 ^ 64));
    }
  };
  auto mmac = [&](int qh, int c) {
    __builtin_amdgcn_s_setprio(1);
    #pragma unroll
    for (int fr = 0; fr < 4; ++fr)
      #pragma unroll
      for (int fq = 0; fq < 2; ++fq) {
        acc[qh * 4 + fr][c * 2 + fq] = __builtin_amdgcn_mfma_f32_16x16x32_bf16(
            aF[fr][0], bF[c][fq][0], acc[qh * 4 + fr][c * 2 + fq], 0, 0, 0);
        acc[qh * 4 + fr][c * 2 + fq] = __builtin_amdgcn_mfma_f32_16x16x32_bf16(
            aF[fr][1], bF[c][fq][1], acc[qh * 4 + fr][c * 2 + fq], 0, 0, 0);
      }
    __builtin_amdgcn_s_setprio(0);
  };

  // prologue: tiles 0,1 in issue order A0B0 | B1 | A1 per tile
  stage(0, 0); stage(2, 0); stage(3, 0); stage(1, 0);
  stage(0, 1); stage(2, 1); stage(3, 1); stage(1, 1);
  VMW(12);   // tile0 A0,B0 landed
  BAR();

  for (int t = 0; t < T - 2; ++t) {
    const int b = t & 1;
    // q0
    readA(0, b); readB(0, b); if (t) stage(1, t + 1);
    VMW(10); BAR(); LGKM0(); mmac(0, 0);
    // q1
    readB(1, b);
    VMW(8); BAR(); LGKM0(); mmac(0, 1);
    // q2
    readA(1, b); stage(0, t + 2); stage(2, t + 2);
    BAR(); LGKM0(); mmac(1, 1);
    // q3 (registers only)
    stage(3, t + 2);
    VMW(10); BAR(); mmac(1, 0);
  }
  {  // t = T-2 (exact drain counts)
    const int b = (T - 2) & 1;
    readA(0, b); readB(0, b); stage(1, T - 1);
    VMW(10); BAR(); LGKM0(); mmac(0, 0);
    readB(1, b);
    VMW(8); BAR(); LGKM0(); mmac(0, 1);
    readA(1, b);
    BAR(); LGKM0(); mmac(1, 1);
    VMW(4); BAR(); mmac(1, 0);
  }
  {  // t = T-1
    const int b = (T - 1) & 1;
    readA(0, b); readB(0, b);
    VMW(2); BAR(); LGKM0(); mmac(0, 0);
    readB(1, b);
    VMW(0); BAR(); LGKM0(); mmac(0, 1);
    readA(1, b);
    BAR(); LGKM0(); mmac(1, 1);
    BAR(); mmac(1, 0);
  }

  // ---- epilogue ----
  // acc value (i8,j,r): row = brow + (i8>>2)*128 + wm*64 + (i8&3)*16 + lhi*4 + r,
  //                     col = bcol + wn*64 + (j>>1)*32 + (j&1)*16 + l15.
  const int wcol = bcol + wn * 64;
  const long rbase = brow + wm * 64;
  char* eplds = lds + w * 4096;

  auto storeTileF32 = [&](int i8, float* dst, bool rope) {
    #pragma unroll
    for (int j = 0; j < 4; ++j)
      #pragma unroll
      for (int r = 0; r < 4; ++r) {
        float v = acc[i8][j][r];
        if (rope) {
          const long row = rbase + (i8 >> 2) * 128 + (i8 & 3) * 16 + lhi * 4 + r;
          const int d = (j >> 1) * 32 + (j & 1) * 16 + l15;
          const float rot = (j < 2) ? -acc[i8][j + 2][r] : acc[i8][j - 2][r];
          v = v * cosp[row * 64 + d] + rot * sinp[row * 64 + d];
        }
        *(float*)(eplds + (lhi * 4 + r) * 256 + ((j >> 1) * 32 + (j & 1) * 16 + l15) * 4) = v;
      }
    asm volatile("s_waitcnt lgkmcnt(0)" ::: "memory");
    #pragma unroll
    for (int t = 0; t < 4; ++t) {
      const int r16 = t * 4 + (lane >> 4);
      const f32x4 v = *(const f32x4*)(eplds + r16 * 256 + (lane & 15) * 16);
      const long row = rbase + (i8 >> 2) * 128 + (i8 & 3) * 16 + r16;
      __builtin_nontemporal_store(v, (f32x4*)(dst + row * 6720 + (lane & 15) * 4));
    }
  };
  auto storeTileBf16 = [&](int i8) {
    #pragma unroll
    for (int j = 0; j < 4; ++j)
      #pragma unroll
      for (int r = 0; r < 4; ++r)
        *(unsigned short*)(eplds + (lhi * 4 + r) * 128 +
                           ((j >> 1) * 32 + (j & 1) * 16 + l15) * 2) = f2bf(acc[i8][j][r]);
    asm volatile("s_waitcnt lgkmcnt(0)" ::: "memory");
    #pragma unroll
    for (int t = 0; t < 2; ++t) {
      const int r16 = t * 8 + (lane >> 3);
      const ui32x4 v = *(const ui32x4*)(eplds + r16 * 128 + (lane & 7) * 16);
      const long row = rbase + (i8 >> 2) * 128 + (i8 & 3) * 16 + r16;
      *(ui32x4*)((char*)qlora + (row * 1536 + wcol) * 2 + (lane & 7) * 16) = v;
    }
  };

  if constexpr (MODE == 0) {
    if (wcol < 1536) {          // q_lora bf16 (cached; re-read by launch2)
      #pragma unroll
      for (int i8 = 0; i8 < 8; ++i8) storeTileBf16(i8);
    } else {                    // compressed_kv -> out cols 6208..6719
      #pragma unroll
      for (int i8 = 0; i8 < 8; ++i8) storeTileF32(i8, out + wcol + 4672, false);
    }
  } else {
    if (isA2) {
      if (wn == 0) {            // k_pe split-K PARTIAL (no RoPE) -> kpart[ks]
        float* pp = kpart + (long)ks * 524288;
        #pragma unroll
        for (int i8 = 0; i8 < 8; ++i8)
          #pragma unroll
          for (int j = 0; j < 4; ++j)
            #pragma unroll
            for (int r = 0; r < 4; ++r) {
              const long row = rbase + (i8 >> 2) * 128 + (i8 & 3) * 16 + lhi * 4 + r;
              const int d = (j >> 1) * 32 + (j & 1) * 16 + l15;
              pp[row * 64 + d] = acc[i8][j][r];
            }
      }                         // wn 1..3: pad cols, dropped
    } else if ((wcol % 192) != 128) {  // q_nope
      #pragma unroll
      for (int i8 = 0; i8 < 8; ++i8) storeTileF32(i8, out + wcol, false);
    } else {                    // q_pe 64-block + RoPE
      #pragma unroll
      for (int i8 = 0; i8 < 8; ++i8) storeTileF32(i8, out + wcol, true);
    }
  }
}

// ---------------- launch ----------------

extern "C" void kernel_launch(void* const* d_in, const int* in_sizes, int n_in,
                              void* d_out, int out_size, void* d_ws, size_t ws_size,
                              hipStream_t stream) {
  const float* x    = (const float*)d_in[0];
  const float* cosp = (const float*)d_in[1];
  const float* sinp = (const float*)d_in[2];
  const float* Wqa  = (const float*)d_in[3];
  const float* Wqb  = (const float*)d_in[4];
  const float* Wkva = (const float*)d_in[5];
  float* out = (float*)d_out;

  char* ws = (char*)d_ws;
  // ws: xb 64MB | w1 17MB | wqb 18MB | ql 24MB | kpart 16MB (total ~139MB)
  __hip_bfloat16* xb  = (__hip_bfloat16*)ws;
  __hip_bfloat16* w1  = (__hip_bfloat16*)(ws + 67108864L);
  __hip_bfloat16* wqb = (__hip_bfloat16*)(ws + 67108864L + 17825792L);
  unsigned short* ql  = (unsigned short*)(ws + 67108864L + 17825792L + 18874368L);
  float* kpart        = (float*)(ws + 67108864L + 17825792L + 18874368L + 25165824L);

  cvt_bf16_kernel<<<2048, 256, 0, stream>>>(x,   (unsigned short*)xb,  8192L * 4096 / 4);
  cvt_bf16_kernel<<<1024, 256, 0, stream>>>(Wqa, (unsigned short*)w1,  1536L * 4096 / 4);
  cvt_pad_kernel<<<640, 256, 0, stream>>>(Wkva, (unsigned short*)(w1 + 1536L * 4096),
                                          576L * 4096 / 4, 640L * 4096 / 4);
  cvt_bf16_kernel<<<1024, 256, 0, stream>>>(Wqb, (unsigned short*)wqb, 6144L * 1536 / 4);

  (void)hipFuncSetAttribute((const void*)&mla_gemm<0>,
                            hipFuncAttributeMaxDynamicSharedMemorySize, 131072);
  (void)hipFuncSetAttribute((const void*)&mla_gemm<1>,
                            hipFuncAttributeMaxDynamicSharedMemorySize, 131072);

  // launch1: x @ w1[0:2048] -> q_lora + compressed_kv. 256 blocks (1 round).
  mla_gemm<0><<<dim3(256), 512, 131072, stream>>>(xb, w1, 4096, nullptr, nullptr,
                                                  nullptr, ql, cosp, sinp, out);
  // launch2: 768 q blocks (exact 3 rounds, bn-major per XCD) + 256 k_pe
  // split-K blocks (T=8).
  mla_gemm<1><<<dim3(1024), 512, 131072, stream>>>((const __hip_bfloat16*)ql, wqb, 1536,
                                                   xb, w1, kpart, ql, cosp, sinp, out);
  // reduce k_pe partials + RoPE -> out cols 6144..6207.
  kpe_reduce_kernel<<<dim3(2048), 256, 0, stream>>>(kpart, cosp, sinp, out);
}